// Round 1
// baseline (12470.461 us; speedup 1.0000x reference)
//
#include <hip/hip_runtime.h>
#include <hip/hip_bf16.h>

#define B_ 16
#define C_ 256
#define S_ 1024
#define L_ 64
#define H_ 8
#define DH_ 64
#define INNER_ 512
#define SPL_ 8
#define SCALE_ 0.125f

// ---------------- q = pp @ Wq[i] : one block per (p,l), 512 outputs ----------
__global__ __launch_bounds__(256) void qk_kernel(const float* __restrict__ prot,
                                                 const float* __restrict__ Wq,
                                                 float* __restrict__ qout, int i) {
    int blk = blockIdx.x;          // p*64 + l
    int p = blk >> 6, l = blk & 63;
    int t = threadIdx.x;
    const float* W  = Wq + (size_t)i * C_ * INNER_;
    const float* pr = prot + ((size_t)(i * SPL_ + p) * C_) * L_ + l;
    float a0 = 0.f, a1 = 0.f;
    for (int c = 0; c < C_; ++c) {
        float pv = pr[(size_t)c * L_];
        a0 += pv * W[c * INNER_ + t];
        a1 += pv * W[c * INNER_ + t + 256];
    }
    qout[(size_t)blk * INNER_ + t]       = a0;
    qout[(size_t)blk * INNER_ + t + 256] = a1;
}

// ---------------- K,V = xp @ Wk/Wv : one block per (b, 8-wide s tile) --------
__global__ __launch_bounds__(256) void kv_kernel(const float* __restrict__ x,
                                                 const float* __restrict__ Wk,
                                                 const float* __restrict__ Wv,
                                                 float* __restrict__ K,
                                                 float* __restrict__ V, int i) {
    __shared__ float xt[C_][8];
    int b  = blockIdx.x >> 7;          // 128 s-blocks per b
    int s0 = (blockIdx.x & 127) * 8;
    int t  = threadIdx.x;
    for (int idx = t; idx < C_ * 8; idx += 256) {
        int c = idx >> 3, sl = idx & 7;
        xt[c][sl] = x[((size_t)b * C_ + c) * S_ + s0 + sl];
    }
    __syncthreads();
    const float* wk = Wk + (size_t)i * C_ * INNER_;
    const float* wv = Wv + (size_t)i * C_ * INNER_;
    float ak0[8] = {0}, ak1[8] = {0}, av0[8] = {0}, av1[8] = {0};
    for (int c = 0; c < C_; ++c) {
        float k0 = wk[c * INNER_ + t], k1 = wk[c * INNER_ + t + 256];
        float v0 = wv[c * INNER_ + t], v1 = wv[c * INNER_ + t + 256];
#pragma unroll
        for (int sl = 0; sl < 8; ++sl) {
            float xv = xt[c][sl];
            ak0[sl] += xv * k0; ak1[sl] += xv * k1;
            av0[sl] += xv * v0; av1[sl] += xv * v1;
        }
    }
    for (int sl = 0; sl < 8; ++sl) {
        size_t row = ((size_t)b * S_ + s0 + sl) * INNER_;
        K[row + t]       = ak0[sl];
        K[row + t + 256] = ak1[sl];
        V[row + t]       = av0[sl];
        V[row + t + 256] = av1[sl];
    }
}

// ---------------- attention: one block per (b,h,p); 2-pass online softmax ----
__global__ __launch_bounds__(256) void attn_kernel(const float* __restrict__ qin,
                                                   const float* __restrict__ K,
                                                   const float* __restrict__ V,
                                                   float* __restrict__ heatp,
                                                   float* __restrict__ distp) {
    __shared__ float kb[64][68];
    __shared__ float vb[64][68];
    __shared__ float ps[64][68];
    __shared__ float m_l[64], d_l[64];
    __shared__ float red[4];
    int blk = blockIdx.x;
    int b = blk >> 6, h = (blk >> 3) & 7, p = blk & 7;
    int t = threadIdx.x;
    int l = t >> 2, j = t & 3;         // 4 threads per l-row

    // q row (l) -> registers (64 floats)
    const float4* q4 = reinterpret_cast<const float4*>(
        qin + ((size_t)(p * L_ + l)) * INNER_ + h * DH_);
    float4 qreg[16];
#pragma unroll
    for (int n = 0; n < 16; ++n) qreg[n] = q4[n];

    // ---- pass A: per-l running max + sum(exp) ----
    float m_t = -1e30f, s_t = 0.f;
    for (int tile = 0; tile < 16; ++tile) {
        const float* Kb = K + ((size_t)(b * S_ + tile * 64)) * INNER_ + h * DH_;
        for (int idx = t; idx < 4096; idx += 256) {
            int sl = idx >> 6, d = idx & 63;
            kb[sl][d] = Kb[(size_t)sl * INNER_ + d];
        }
        __syncthreads();
#pragma unroll
        for (int n = 0; n < 16; ++n) {
            int sl = j * 16 + n;
            const float4* k4 = reinterpret_cast<const float4*>(&kb[sl][0]);
            float acc = 0.f;
#pragma unroll
            for (int d4 = 0; d4 < 16; ++d4) {
                float4 qv = qreg[d4], kv = k4[d4];
                acc += qv.x * kv.x + qv.y * kv.y + qv.z * kv.z + qv.w * kv.w;
            }
            acc *= SCALE_;
            if (acc > m_t) { s_t = s_t * __expf(m_t - acc) + 1.f; m_t = acc; }
            else           { s_t += __expf(acc - m_t); }
        }
        __syncthreads();
    }
#pragma unroll
    for (int off = 1; off < 4; off <<= 1) {
        float mo = __shfl_xor(m_t, off, 64);
        float so = __shfl_xor(s_t, off, 64);
        float mn = fmaxf(m_t, mo);
        s_t = s_t * __expf(m_t - mn) + so * __expf(mo - mn);
        m_t = mn;
    }
    if (j == 0) { m_l[l] = m_t; d_l[l] = s_t; }
    __syncthreads();

    // ---- pass B: recompute, normalize, PV + heat ----
    float myM = m_l[l], myD = d_l[l];
    float4 o[4];
#pragma unroll
    for (int n = 0; n < 4; ++n) o[n] = make_float4(0.f, 0.f, 0.f, 0.f);

    for (int tile = 0; tile < 16; ++tile) {
        const float* Kb = K + ((size_t)(b * S_ + tile * 64)) * INNER_ + h * DH_;
        const float* Vb = V + ((size_t)(b * S_ + tile * 64)) * INNER_ + h * DH_;
        for (int idx = t; idx < 4096; idx += 256) {
            int sl = idx >> 6, d = idx & 63;
            kb[sl][d] = Kb[(size_t)sl * INNER_ + d];
            vb[sl][d] = Vb[(size_t)sl * INNER_ + d];
        }
        __syncthreads();
#pragma unroll
        for (int n = 0; n < 16; ++n) {
            int sl = j * 16 + n;
            const float4* k4 = reinterpret_cast<const float4*>(&kb[sl][0]);
            float acc = 0.f;
#pragma unroll
            for (int d4 = 0; d4 < 16; ++d4) {
                float4 qv = qreg[d4], kv = k4[d4];
                acc += qv.x * kv.x + qv.y * kv.y + qv.z * kv.z + qv.w * kv.w;
            }
            acc *= SCALE_;
            ps[l][sl] = __expf(acc - myM) / myD;
        }
        __syncthreads();
#pragma unroll 8
        for (int sl = 0; sl < 64; ++sl) {
            float pv = ps[l][sl];
            const float4* v4 = reinterpret_cast<const float4*>(&vb[sl][j * 16]);
            o[0].x += pv * v4[0].x; o[0].y += pv * v4[0].y;
            o[0].z += pv * v4[0].z; o[0].w += pv * v4[0].w;
            o[1].x += pv * v4[1].x; o[1].y += pv * v4[1].y;
            o[1].z += pv * v4[1].z; o[1].w += pv * v4[1].w;
            o[2].x += pv * v4[2].x; o[2].y += pv * v4[2].y;
            o[2].z += pv * v4[2].z; o[2].w += pv * v4[2].w;
            o[3].x += pv * v4[3].x; o[3].y += pv * v4[3].y;
            o[3].z += pv * v4[3].z; o[3].w += pv * v4[3].w;
        }
        if (t < 64) {
            float hs = 0.f;
            for (int ll = 0; ll < 64; ++ll) hs += ps[ll][t];
            heatp[(((size_t)h * B_ + b) * SPL_ + p) * S_ + tile * 64 + t] = hs;
        }
        __syncthreads();
    }

    // ---- dist partial: sum over (l, my 16 d) of (q - out)^2 ----
    float dsum = 0.f;
#pragma unroll
    for (int m = 0; m < 4; ++m) {
        float4 qv = qreg[j * 4 + m];
        float4 ov = o[m];
        float dx = qv.x - ov.x, dy = qv.y - ov.y, dz = qv.z - ov.z, dw = qv.w - ov.w;
        dsum += dx * dx + dy * dy + dz * dz + dw * dw;
    }
    for (int off = 32; off; off >>= 1) dsum += __shfl_down(dsum, off, 64);
    if ((t & 63) == 0) red[t >> 6] = dsum;
    __syncthreads();
    if (t == 0) {
        float tot = red[0] + red[1] + red[2] + red[3];
        distp[((size_t)b * SPL_ + p) * H_ + h] = tot;
    }
}

// ---------------- finalize: deterministic argmax + dist write ----------------
__global__ __launch_bounds__(256) void fin_kernel(const float* __restrict__ heatp,
                                                  const float* __restrict__ distp,
                                                  float* __restrict__ out, int i) {
    __shared__ float rv[256];
    __shared__ int   ri[256];
    int b = blockIdx.x >> 3, p = blockIdx.x & 7;
    int t = threadIdx.x;
    float best = -1e30f; int bidx = 0;
    for (int s = t; s < S_; s += 256) {
        float hv = 0.f;
#pragma unroll
        for (int h = 0; h < 8; ++h)
            hv += heatp[(((size_t)h * B_ + b) * SPL_ + p) * S_ + s];
        if (hv > best) { best = hv; bidx = s; }
    }
    rv[t] = best; ri[t] = bidx;
    __syncthreads();
    if (t == 0) {
        for (int u = 1; u < 256; ++u) {
            if (rv[u] > best || (rv[u] == best && ri[u] < bidx)) { best = rv[u]; bidx = ri[u]; }
        }
        out[384 + b * 24 + i * SPL_ + p] = (float)bidx;
        float ds = 0.f;
        for (int h = 0; h < 8; ++h) ds += distp[((size_t)b * SPL_ + p) * H_ + h];
        out[b * 24 + i * SPL_ + p] = ds / (float)(L_ * INNER_);
    }
}

extern "C" void kernel_launch(void* const* d_in, const int* in_sizes, int n_in,
                              void* d_out, int out_size, void* d_ws, size_t ws_size,
                              hipStream_t stream) {
    const float* x    = (const float*)d_in[0];
    const float* prot = (const float*)d_in[1];
    const float* Wq   = (const float*)d_in[2];
    const float* Wk   = (const float*)d_in[3];
    const float* Wv   = (const float*)d_in[4];
    float* out = (float*)d_out;
    float* ws  = (float*)d_ws;

    float* q     = ws;                       // 512*512           = 262144
    float* K     = q + 512 * 512;            // 16*1024*512       = 8388608
    float* V     = K + (size_t)B_ * S_ * INNER_;
    float* heatp = V + (size_t)B_ * S_ * INNER_;   // 8*16*8*1024 = 1048576
    float* distp = heatp + (size_t)H_ * B_ * SPL_ * S_;  // 16*8*8 = 1024

    for (int i = 0; i < 3; ++i) {
        qk_kernel  <<<512,  256, 0, stream>>>(prot, Wq, q, i);
        kv_kernel  <<<2048, 256, 0, stream>>>(x, Wk, Wv, K, V, i);
        attn_kernel<<<1024, 256, 0, stream>>>(q, K, V, heatp, distp);
        fin_kernel <<<128,  256, 0, stream>>>(heatp, distp, out, i);
    }
}

// Round 2
// 1129.571 us; speedup vs baseline: 11.0400x; 11.0400x over previous
//
#include <hip/hip_runtime.h>
#include <hip/hip_bf16.h>

#define Bq 16
#define Cc 256
#define Ss 1024
#define Ll 64
#define Hh 8
#define DHd 64
#define INN 512
#define Pp 8
#define SCALE_ 0.125f

typedef short s16x8 __attribute__((ext_vector_type(8)));
typedef float f32x4 __attribute__((ext_vector_type(4)));

__device__ __forceinline__ unsigned short f2bf(float f) {
    unsigned u = __builtin_bit_cast(unsigned, f);
    u += 0x7FFF + ((u >> 16) & 1);
    return (unsigned short)(u >> 16);
}
__device__ __forceinline__ float bf2f(unsigned short h) {
    return __builtin_bit_cast(float, (unsigned)h << 16);
}

// ---------------- q = pp @ Wq[i] : f32, accurate, tiny ----------
__global__ __launch_bounds__(256) void qk_kernel(const float* __restrict__ prot,
                                                 const float* __restrict__ Wq,
                                                 float* __restrict__ qout, int i) {
    int blk = blockIdx.x;          // p*64 + l
    int p = blk >> 6, l = blk & 63;
    int t = threadIdx.x;
    const float* W  = Wq + (size_t)i * Cc * INN;
    const float* pr = prot + ((size_t)(i * Pp + p) * Cc) * Ll + l;
    float a0 = 0.f, a1 = 0.f;
    for (int c = 0; c < Cc; ++c) {
        float pv = pr[(size_t)c * Ll];
        a0 += pv * W[c * INN + t];
        a1 += pv * W[c * INN + t + 256];
    }
    qout[(size_t)blk * INN + t]       = a0;
    qout[(size_t)blk * INN + t + 256] = a1;
}

// ---------------- K,V projection: f32 compute; emits K hi/lo u32 + V^T bf16 --
__global__ __launch_bounds__(256) void kv_kernel(const float* __restrict__ x,
        const float* __restrict__ Wk, const float* __restrict__ Wv,
        unsigned* __restrict__ Khl, unsigned short* __restrict__ Vt, int i) {
    __shared__ float xt[Cc][8];
    int b  = blockIdx.x >> 7;
    int s0 = (blockIdx.x & 127) * 8;
    int t  = threadIdx.x;
    for (int idx = t; idx < Cc * 8; idx += 256) {
        int cch = idx >> 3, sl = idx & 7;
        xt[cch][sl] = x[((size_t)b * Cc + cch) * Ss + s0 + sl];
    }
    __syncthreads();
    const float* wk = Wk + (size_t)i * Cc * INN;
    const float* wv = Wv + (size_t)i * Cc * INN;
    float ak0[8] = {0}, ak1[8] = {0}, av0[8] = {0}, av1[8] = {0};
    for (int cc = 0; cc < Cc; ++cc) {
        float k0 = wk[cc * INN + t], k1 = wk[cc * INN + t + 256];
        float v0 = wv[cc * INN + t], v1 = wv[cc * INN + t + 256];
#pragma unroll
        for (int sl = 0; sl < 8; ++sl) {
            float xv = xt[cc][sl];
            ak0[sl] += xv * k0; ak1[sl] += xv * k1;
            av0[sl] += xv * v0; av1[sl] += xv * v1;
        }
    }
#pragma unroll
    for (int half = 0; half < 2; ++half) {
        int n  = t + half * 256;
        int hh = n >> 6, dh = n & 63;
        const float* ak = half ? ak1 : ak0;
        const float* av = half ? av1 : av0;
#pragma unroll
        for (int sl = 0; sl < 8; ++sl) {
            float v = ak[sl];
            unsigned short hi = f2bf(v);
            unsigned short lo = f2bf(v - bf2f(hi));
            Khl[((size_t)(b * Hh + hh) * Ss + s0 + sl) * DHd + dh] =
                ((unsigned)hi << 16) | lo;
        }
        unsigned short vs[8];
#pragma unroll
        for (int sl = 0; sl < 8; ++sl) vs[sl] = f2bf(av[sl]);
        uint4 w;
        w.x = vs[0] | ((unsigned)vs[1] << 16);
        w.y = vs[2] | ((unsigned)vs[3] << 16);
        w.z = vs[4] | ((unsigned)vs[5] << 16);
        w.w = vs[6] | ((unsigned)vs[7] << 16);
        *(uint4*)(Vt + ((size_t)(b * Hh + hh) * DHd + dh) * Ss + s0) = w;
    }
}

// ---------------- pass A: approx scores (hi*hi) -> per-row m, d ---------------
__global__ __launch_bounds__(512, 2) void passA_kernel(
        const float* __restrict__ q, const unsigned* __restrict__ Khl,
        float* __restrict__ md) {
    __shared__ unsigned Klds[64 * 64];   // 16KB, 16B-group swizzled
    int bx = blockIdx.x;
    int b = bx >> 4, h = (bx >> 1) & 7, sh = bx & 1;
    int t = threadIdx.x;
    int p = t >> 6, lane = t & 63, c = lane & 15, g = lane >> 4;

    s16x8 qh[4][2];
#pragma unroll
    for (int mt = 0; mt < 4; ++mt)
#pragma unroll
      for (int kt = 0; kt < 2; ++kt) {
        const float* qp = q + (size_t)(p * 64 + mt * 16 + c) * INN + h * 64 + kt * 32 + g * 8;
        s16x8 f;
#pragma unroll
        for (int e = 0; e < 8; ++e) f[e] = (short)f2bf(qp[e] * SCALE_);
        qh[mt][kt] = f;
      }

    float m[4][4], d[4][4];
#pragma unroll
    for (int a = 0; a < 4; ++a)
#pragma unroll
      for (int r = 0; r < 4; ++r) { m[a][r] = -3e38f; d[a][r] = 0.f; }

    for (int ch = 0; ch < 8; ++ch) {
        int sbase = sh * 512 + ch * 64;
#pragma unroll
        for (int it = 0; it < 2; ++it) {
            int gi = t + it * 512;
            int srow = gi >> 4, d4 = gi & 15;
            const uint4* src = (const uint4*)(Khl +
                ((size_t)((b * Hh + h) * Ss + sbase + srow)) * DHd) + d4;
            ((uint4*)Klds)[srow * 16 + (d4 ^ (srow & 7))] = *src;
        }
        __syncthreads();

        f32x4 acc[4][4];
#pragma unroll
        for (int a = 0; a < 4; ++a)
#pragma unroll
          for (int s = 0; s < 4; ++s) acc[a][s] = (f32x4){0.f, 0.f, 0.f, 0.f};

#pragma unroll
        for (int kt = 0; kt < 2; ++kt)
#pragma unroll
          for (int st = 0; st < 4; ++st) {
            int srow = st * 16 + c;
            uint4 wa = ((const uint4*)Klds)[srow * 16 + ((kt * 8 + 2 * g) ^ (c & 7))];
            uint4 wb = ((const uint4*)Klds)[srow * 16 + ((kt * 8 + 2 * g + 1) ^ (c & 7))];
            s16x8 kh;
            kh[0] = (short)(wa.x >> 16); kh[1] = (short)(wa.y >> 16);
            kh[2] = (short)(wa.z >> 16); kh[3] = (short)(wa.w >> 16);
            kh[4] = (short)(wb.x >> 16); kh[5] = (short)(wb.y >> 16);
            kh[6] = (short)(wb.z >> 16); kh[7] = (short)(wb.w >> 16);
#pragma unroll
            for (int mt = 0; mt < 4; ++mt)
                acc[mt][st] = __builtin_amdgcn_mfma_f32_16x16x32_bf16(
                    qh[mt][kt], kh, acc[mt][st], 0, 0, 0);
          }

#pragma unroll
        for (int mt = 0; mt < 4; ++mt)
#pragma unroll
          for (int r = 0; r < 4; ++r) {
            float rm = fmaxf(fmaxf(acc[mt][0][r], acc[mt][1][r]),
                             fmaxf(acc[mt][2][r], acc[mt][3][r]));
            rm = fmaxf(rm, __shfl_xor(rm, 1));
            rm = fmaxf(rm, __shfl_xor(rm, 2));
            rm = fmaxf(rm, __shfl_xor(rm, 4));
            rm = fmaxf(rm, __shfl_xor(rm, 8));
            float mo = m[mt][r];
            float mn = fmaxf(mo, rm);
            float es = __expf(acc[mt][0][r] - mn) + __expf(acc[mt][1][r] - mn)
                     + __expf(acc[mt][2][r] - mn) + __expf(acc[mt][3][r] - mn);
            es += __shfl_xor(es, 1); es += __shfl_xor(es, 2);
            es += __shfl_xor(es, 4); es += __shfl_xor(es, 8);
            d[mt][r] = d[mt][r] * __expf(mo - mn) + es;
            m[mt][r] = mn;
          }
        __syncthreads();
    }

    if (c == 0) {
#pragma unroll
        for (int mt = 0; mt < 4; ++mt)
#pragma unroll
          for (int r = 0; r < 4; ++r) {
            int row = mt * 16 + g * 4 + r;
            size_t idx = (((size_t)((b * Hh + h) * 2 + sh) * Pp + p) * Ll + row) * 2;
            md[idx] = m[mt][r];
            md[idx + 1] = d[mt][r];
          }
    }
}

// ---------------- pass B: exact scores (3-mfma) -> probs, heat, PV -----------
__global__ __launch_bounds__(512, 2) void passB_kernel(
        const float* __restrict__ q, const unsigned* __restrict__ Khl,
        const unsigned short* __restrict__ Vt, const float* __restrict__ md,
        float* __restrict__ heatp, float* __restrict__ outp) {
    __shared__ unsigned Klds[64 * 64];            // 16KB
    __shared__ unsigned short Vtlds[64 * 64];     // 8KB
    __shared__ unsigned short plds[8][64 * 32];   // 32KB, per-wave private
    int bx = blockIdx.x;
    int b = bx >> 4, h = (bx >> 1) & 7, sh = bx & 1;
    int t = threadIdx.x;
    int p = t >> 6, lane = t & 63, c = lane & 15, g = lane >> 4;

    float mfin[4][4], rdf[4][4];
#pragma unroll
    for (int mt = 0; mt < 4; ++mt)
#pragma unroll
      for (int r = 0; r < 4; ++r) {
        int row = mt * 16 + g * 4 + r;
        size_t i0 = (((size_t)((b * Hh + h) * 2 + 0) * Pp + p) * Ll + row) * 2;
        size_t i1 = (((size_t)((b * Hh + h) * 2 + 1) * Pp + p) * Ll + row) * 2;
        float m0 = md[i0], d0 = md[i0 + 1], m1 = md[i1], d1 = md[i1 + 1];
        float mm = fmaxf(m0, m1);
        float dd = d0 * __expf(m0 - mm) + d1 * __expf(m1 - mm);
        mfin[mt][r] = mm; rdf[mt][r] = 1.0f / dd;
      }

    s16x8 qh[4][2], ql[4][2];
#pragma unroll
    for (int mt = 0; mt < 4; ++mt)
#pragma unroll
      for (int kt = 0; kt < 2; ++kt) {
        const float* qp = q + (size_t)(p * 64 + mt * 16 + c) * INN + h * 64 + kt * 32 + g * 8;
        s16x8 fh, fl;
#pragma unroll
        for (int e = 0; e < 8; ++e) {
            float v = qp[e] * SCALE_;
            unsigned short hi = f2bf(v);
            fh[e] = (short)hi;
            fl[e] = (short)f2bf(v - bf2f(hi));
        }
        qh[mt][kt] = fh; ql[mt][kt] = fl;
      }

    f32x4 o[4][4];   // [mt][dht]
#pragma unroll
    for (int a = 0; a < 4; ++a)
#pragma unroll
      for (int s = 0; s < 4; ++s) o[a][s] = (f32x4){0.f, 0.f, 0.f, 0.f};

    for (int ch = 0; ch < 8; ++ch) {
        int sbase = sh * 512 + ch * 64;
#pragma unroll
        for (int it = 0; it < 2; ++it) {
            int gi = t + it * 512;
            int srow = gi >> 4, d4 = gi & 15;
            const uint4* src = (const uint4*)(Khl +
                ((size_t)((b * Hh + h) * Ss + sbase + srow)) * DHd) + d4;
            ((uint4*)Klds)[srow * 16 + (d4 ^ (srow & 7))] = *src;
        }
        {
            int dh = t >> 3, sg = t & 7;
            const uint4* vsrc = (const uint4*)(Vt +
                ((size_t)(b * Hh + h) * DHd + dh) * Ss + sbase + sg * 8);
            ((uint4*)Vtlds)[dh * 8 + (sg ^ (dh & 7))] = *vsrc;
        }
        __syncthreads();

#pragma unroll
        for (int half = 0; half < 2; ++half) {
            f32x4 sacc[4][2];
#pragma unroll
            for (int a = 0; a < 4; ++a)
#pragma unroll
              for (int s = 0; s < 2; ++s) sacc[a][s] = (f32x4){0.f, 0.f, 0.f, 0.f};

#pragma unroll
            for (int kt = 0; kt < 2; ++kt)
#pragma unroll
              for (int s2 = 0; s2 < 2; ++s2) {
                int st = half * 2 + s2;
                int srow = st * 16 + c;
                uint4 wa = ((const uint4*)Klds)[srow * 16 + ((kt * 8 + 2 * g) ^ (c & 7))];
                uint4 wb = ((const uint4*)Klds)[srow * 16 + ((kt * 8 + 2 * g + 1) ^ (c & 7))];
                s16x8 kh, kl;
                kh[0] = (short)(wa.x >> 16); kl[0] = (short)(wa.x & 0xFFFF);
                kh[1] = (short)(wa.y >> 16); kl[1] = (short)(wa.y & 0xFFFF);
                kh[2] = (short)(wa.z >> 16); kl[2] = (short)(wa.z & 0xFFFF);
                kh[3] = (short)(wa.w >> 16); kl[3] = (short)(wa.w & 0xFFFF);
                kh[4] = (short)(wb.x >> 16); kl[4] = (short)(wb.x & 0xFFFF);
                kh[5] = (short)(wb.y >> 16); kl[5] = (short)(wb.y & 0xFFFF);
                kh[6] = (short)(wb.z >> 16); kl[6] = (short)(wb.z & 0xFFFF);
                kh[7] = (short)(wb.w >> 16); kl[7] = (short)(wb.w & 0xFFFF);
#pragma unroll
                for (int mt = 0; mt < 4; ++mt) {
                    sacc[mt][s2] = __builtin_amdgcn_mfma_f32_16x16x32_bf16(
                        qh[mt][kt], kh, sacc[mt][s2], 0, 0, 0);
                    sacc[mt][s2] = __builtin_amdgcn_mfma_f32_16x16x32_bf16(
                        qh[mt][kt], kl, sacc[mt][s2], 0, 0, 0);
                    sacc[mt][s2] = __builtin_amdgcn_mfma_f32_16x16x32_bf16(
                        ql[mt][kt], kh, sacc[mt][s2], 0, 0, 0);
                }
              }

#pragma unroll
            for (int s2 = 0; s2 < 2; ++s2) {
                int st = half * 2 + s2;
                float hs = 0.f;
#pragma unroll
                for (int mt = 0; mt < 4; ++mt)
#pragma unroll
                  for (int r = 0; r < 4; ++r) {
                    float pv = __expf(sacc[mt][s2][r] - mfin[mt][r]) * rdf[mt][r];
                    hs += pv;
                    int row = mt * 16 + g * 4 + r;
                    int colh = s2 * 16 + c;
                    plds[p][row * 32 + (((colh >> 3) ^ ((row >> 2) & 3)) << 3) + (colh & 7)]
                        = f2bf(pv);
                  }
                hs += __shfl_xor(hs, 16);
                hs += __shfl_xor(hs, 32);
                if (g == 0)
                    heatp[((size_t)(h * Bq + b) * Pp + p) * Ss + sbase + st * 16 + c] = hs;
            }

            s16x8 pa[4], vb[4];
#pragma unroll
            for (int mt = 0; mt < 4; ++mt) {
                int row = mt * 16 + c;
                uint4 w = ((const uint4*)plds[p])[row * 4 + (g ^ ((row >> 2) & 3))];
                pa[mt] = __builtin_bit_cast(s16x8, w);
            }
#pragma unroll
            for (int dht = 0; dht < 4; ++dht) {
                int row = dht * 16 + c;
                uint4 w = ((const uint4*)Vtlds)[row * 8 + ((half * 4 + g) ^ (c & 7))];
                vb[dht] = __builtin_bit_cast(s16x8, w);
            }
#pragma unroll
            for (int mt = 0; mt < 4; ++mt)
#pragma unroll
              for (int dht = 0; dht < 4; ++dht)
                o[mt][dht] = __builtin_amdgcn_mfma_f32_16x16x32_bf16(
                    pa[mt], vb[dht], o[mt][dht], 0, 0, 0);
        }
        __syncthreads();
    }

#pragma unroll
    for (int mt = 0; mt < 4; ++mt)
#pragma unroll
      for (int dht = 0; dht < 4; ++dht)
#pragma unroll
        for (int r = 0; r < 4; ++r) {
            int row = mt * 16 + g * 4 + r;
            outp[(((((size_t)sh * Bq + b) * Hh + h) * Pp + p) * Ll + row) * DHd
                 + dht * 16 + c] = o[mt][dht][r];
        }
}

// ---------------- finalize: deterministic argmax + dist ----------------------
__global__ __launch_bounds__(256) void fin_kernel(
        const float* __restrict__ heatp, const float* __restrict__ outp,
        const float* __restrict__ q, float* __restrict__ out, int i) {
    __shared__ float rv[256];
    __shared__ int   ri[256];
    __shared__ float rs[4];
    int b = blockIdx.x >> 3, p = blockIdx.x & 7;
    int t = threadIdx.x;
    float best = -1e30f; int bidx = 0;
    for (int s = t; s < Ss; s += 256) {
        float hv = 0.f;
#pragma unroll
        for (int h = 0; h < 8; ++h)
            hv += heatp[((size_t)(h * Bq + b) * Pp + p) * Ss + s];
        if (hv > best) { best = hv; bidx = s; }
    }
    rv[t] = best; ri[t] = bidx;
    __syncthreads();
    if (t == 0) {
        for (int u = 1; u < 256; ++u)
            if (rv[u] > best || (rv[u] == best && ri[u] < bidx)) { best = rv[u]; bidx = ri[u]; }
        out[384 + b * 24 + i * Pp + p] = (float)bidx;
    }
    const size_t HALF = (size_t)Bq * Hh * Pp * Ll * DHd;
    float sum = 0.f;
    for (int idx = t; idx < Ll * INN; idx += 256) {
        int l = idx >> 9, n = idx & 511;
        int hh = n >> 6, dh = n & 63;
        float qv = q[(size_t)(p * Ll + l) * INN + n];
        size_t base = ((((size_t)b * Hh + hh) * Pp + p) * Ll + l) * DHd + dh;
        float ov = outp[base] + outp[HALF + base];
        float df = qv - ov;
        sum += df * df;
    }
    for (int off = 32; off; off >>= 1) sum += __shfl_down(sum, off);
    if ((t & 63) == 0) rs[t >> 6] = sum;
    __syncthreads();
    if (t == 0)
        out[b * 24 + i * Pp + p] = (rs[0] + rs[1] + rs[2] + rs[3]) / (float)(Ll * INN);
}

extern "C" void kernel_launch(void* const* d_in, const int* in_sizes, int n_in,
                              void* d_out, int out_size, void* d_ws, size_t ws_size,
                              hipStream_t stream) {
    const float* x    = (const float*)d_in[0];
    const float* prot = (const float*)d_in[1];
    const float* Wq   = (const float*)d_in[2];
    const float* Wk   = (const float*)d_in[3];
    const float* Wv   = (const float*)d_in[4];
    float* out = (float*)d_out;
    float* ws  = (float*)d_ws;

    float*          qbuf  = ws;                                   // 262144 f32
    unsigned*       Khl   = (unsigned*)(ws + 262144);             // 8388608 u32
    unsigned short* Vt    = (unsigned short*)(ws + 262144 + 8388608); // 8388608 u16
    float*          heatp = ws + 262144 + 8388608 + 4194304;      // 1048576 f32
    float*          md    = heatp + 1048576;                      // 262144 f32
    float*          outp  = md + 262144;                          // 8388608 f32

    for (int i = 0; i < 3; ++i) {
        qk_kernel  <<<512,  256, 0, stream>>>(prot, Wq, qbuf, i);
        kv_kernel  <<<2048, 256, 0, stream>>>(x, Wk, Wv, Khl, Vt, i);
        passA_kernel<<<256, 512, 0, stream>>>(qbuf, Khl, md);
        passB_kernel<<<256, 512, 0, stream>>>(qbuf, Khl, Vt, md, heatp, outp);
        fin_kernel <<<128,  256, 0, stream>>>(heatp, outp, qbuf, out, i);
    }
}

// Round 3
// 811.888 us; speedup vs baseline: 15.3598x; 1.3913x over previous
//
#include <hip/hip_runtime.h>
#include <hip/hip_bf16.h>

#define Bq 16
#define Cc 256
#define Ss 1024
#define Ll 64
#define Hh 8
#define DHd 64
#define INN 512
#define Pp 8
// SCALE * log2(e) folded into q so scores are in log2 domain
#define KSC 0.18033688011111772f

typedef short s16x8 __attribute__((ext_vector_type(8)));
typedef float f32x4 __attribute__((ext_vector_type(4)));

__device__ __forceinline__ unsigned short f2bf(float f) {
    unsigned u = __builtin_bit_cast(unsigned, f);
    u += 0x7FFF + ((u >> 16) & 1);
    return (unsigned short)(u >> 16);
}
__device__ __forceinline__ float bf2f(unsigned short h) {
    return __builtin_bit_cast(float, (unsigned)h << 16);
}

// ---------- W transpose + bf16 hi/lo split: Wk -> Wth/Wtl, Wv -> Wvh ---------
__global__ __launch_bounds__(256) void wsplit_kernel(
        const float* __restrict__ Wk, const float* __restrict__ Wv,
        unsigned short* __restrict__ Wth, unsigned short* __restrict__ Wtl,
        unsigned short* __restrict__ Wvh) {
    __shared__ float tile[64][65];
    int blk = blockIdx.x;              // 48 = i*16 + mat*8 + ns
    int i = blk >> 4, rem = blk & 15, mat = rem >> 3, ns = rem & 7;
    int n0 = ns * 64, t = threadIdx.x;
    const float* W = (mat == 0 ? Wk : Wv) + (size_t)i * Cc * INN;
    for (int cb = 0; cb < 4; ++cb) {
        int c0 = cb * 64;
#pragma unroll
        for (int it = 0; it < 16; ++it) {
            int idx = t + it * 256; int cc = idx >> 6, nn = idx & 63;
            tile[cc][nn] = W[(size_t)(c0 + cc) * INN + n0 + nn];
        }
        __syncthreads();
#pragma unroll
        for (int it = 0; it < 16; ++it) {
            int idx = t + it * 256; int nn = idx >> 6, cc = idx & 63;
            float v = tile[cc][nn];
            unsigned short hi = f2bf(v);
            size_t o = (size_t)i * 131072 + (size_t)(n0 + nn) * Cc + c0 + cc;
            if (mat == 0) { Wth[o] = hi; Wtl[o] = f2bf(v - bf2f(hi)); }
            else          { Wvh[o] = hi; }
        }
        __syncthreads();
    }
}

// ---------- q = pp @ Wq[i] : f32, LDS-staged prototype column, all i ---------
__global__ __launch_bounds__(256) void qk_kernel(const float* __restrict__ prot,
                                                 const float* __restrict__ Wq,
                                                 float* __restrict__ qout) {
    __shared__ float pcol[256];
    int blk = blockIdx.x;              // 1536 = i*512 + p*64 + l
    int i = blk >> 9, pl = blk & 511, p = pl >> 6, l = pl & 63;
    int t = threadIdx.x;
    const float* W = Wq + (size_t)i * Cc * INN;
    pcol[t] = prot[((size_t)(i * Pp + p) * Cc + t) * Ll + l];
    __syncthreads();
    float a0 = 0.f, a1 = 0.f;
#pragma unroll 8
    for (int c = 0; c < Cc; ++c) {
        float pv = pcol[c];
        a0 += pv * W[c * INN + t];
        a1 += pv * W[c * INN + t + 256];
    }
    float* qo = qout + (size_t)i * 262144 + (size_t)pl * INN;
    qo[t] = a0; qo[t + 256] = a1;
}

// ---------- K,V projection via bf16 split-MFMA; no LDS ----------------------
__global__ __launch_bounds__(512) void kv_kernel(
        const float* __restrict__ x, const unsigned short* __restrict__ WthA,
        const unsigned short* __restrict__ WtlA, const unsigned short* __restrict__ WvhA,
        unsigned short* __restrict__ Kh, unsigned short* __restrict__ Kl,
        unsigned short* __restrict__ Vt, int i) {
    int blk = blockIdx.x;              // 256 = b*16 + sb
    int b = blk >> 4, sb = blk & 15;
    int t = threadIdx.x, w = t >> 6, lane = t & 63, c = lane & 15, g = lane >> 4;
    int sw = w >> 1, nh = w & 1;
    const unsigned short* wth = WthA + (size_t)i * 131072;
    const unsigned short* wtl = WtlA + (size_t)i * 131072;
    const unsigned short* wvh = WvhA + (size_t)i * 131072;
    int s_lane = sb * 64 + sw * 16 + c;
    const float* xp = x + (size_t)b * Cc * Ss + s_lane;

    f32x4 accK[16], accV[16];
#pragma unroll
    for (int nt = 0; nt < 16; ++nt) {
        accK[nt] = (f32x4){0.f, 0.f, 0.f, 0.f};
        accV[nt] = (f32x4){0.f, 0.f, 0.f, 0.f};
    }

#pragma unroll
    for (int cs = 0; cs < 8; ++cs) {
        int c0 = cs * 32 + g * 8;
        s16x8 ah, al;
#pragma unroll
        for (int e = 0; e < 8; ++e) {
            float v = xp[(size_t)(c0 + e) * Ss];
            unsigned short hi = f2bf(v);
            ah[e] = (short)hi;
            al[e] = (short)f2bf(v - bf2f(hi));
        }
#pragma unroll
        for (int nt = 0; nt < 16; ++nt) {
            int n = nh * 256 + nt * 16 + c;
            s16x8 bh = __builtin_bit_cast(s16x8,
                *(const uint4*)(wth + (size_t)n * Cc + c0));
            s16x8 bl = __builtin_bit_cast(s16x8,
                *(const uint4*)(wtl + (size_t)n * Cc + c0));
            s16x8 bv = __builtin_bit_cast(s16x8,
                *(const uint4*)(wvh + (size_t)n * Cc + c0));
            accK[nt] = __builtin_amdgcn_mfma_f32_16x16x32_bf16(ah, bh, accK[nt], 0, 0, 0);
            accK[nt] = __builtin_amdgcn_mfma_f32_16x16x32_bf16(ah, bl, accK[nt], 0, 0, 0);
            accK[nt] = __builtin_amdgcn_mfma_f32_16x16x32_bf16(al, bh, accK[nt], 0, 0, 0);
            accV[nt] = __builtin_amdgcn_mfma_f32_16x16x32_bf16(ah, bv, accV[nt], 0, 0, 0);
        }
    }

    int s0 = sb * 64 + sw * 16 + g * 4;
#pragma unroll
    for (int nt = 0; nt < 16; ++nt) {
        int n = nh * 256 + nt * 16 + c;
        int hh = n >> 6, dh = n & 63;
        size_t kbase = ((size_t)(b * Hh + hh) * Ss + s0) * DHd + dh;
#pragma unroll
        for (int r = 0; r < 4; ++r) {
            float kvv = accK[nt][r];
            unsigned short hi = f2bf(kvv);
            Kh[kbase + (size_t)r * DHd] = hi;
            Kl[kbase + (size_t)r * DHd] = f2bf(kvv - bf2f(hi));
        }
        unsigned short v0 = f2bf(accV[nt][0]), v1 = f2bf(accV[nt][1]);
        unsigned short v2 = f2bf(accV[nt][2]), v3 = f2bf(accV[nt][3]);
        uint2 pk;
        pk.x = v0 | ((unsigned)v1 << 16);
        pk.y = v2 | ((unsigned)v3 << 16);
        *(uint2*)(Vt + ((size_t)(b * Hh + hh) * DHd + dh) * Ss + s0) = pk;
    }
}

// ---------- pass A: hi-only scores -> d = sum exp2(s), no max ----------------
__global__ __launch_bounds__(512) void passA_kernel(
        const float* __restrict__ q, const unsigned short* __restrict__ Kh,
        float* __restrict__ md, int i) {
    __shared__ unsigned short Klds[64 * 64];   // 8KB swizzled
    int bx = blockIdx.x;
    int b = bx >> 4, h = (bx >> 1) & 7, sh = bx & 1;
    int t = threadIdx.x, p = t >> 6, lane = t & 63, c = lane & 15, g = lane >> 4;
    const float* qb = q + (size_t)i * 262144;

    s16x8 qh[4][2];
#pragma unroll
    for (int mt = 0; mt < 4; ++mt)
#pragma unroll
      for (int kt = 0; kt < 2; ++kt) {
        const float* qp = qb + (size_t)(p * 64 + mt * 16 + c) * INN + h * 64 + kt * 32 + g * 8;
        s16x8 f;
#pragma unroll
        for (int e = 0; e < 8; ++e) f[e] = (short)f2bf(qp[e] * KSC);
        qh[mt][kt] = f;
      }

    float d[4][4];
#pragma unroll
    for (int a = 0; a < 4; ++a)
#pragma unroll
      for (int r = 0; r < 4; ++r) d[a][r] = 0.f;

    for (int ch = 0; ch < 8; ++ch) {
        int sbase = sh * 512 + ch * 64;
        {
            int srow = t >> 3, g8 = t & 7;
            ((uint4*)Klds)[srow * 8 + (g8 ^ (srow & 7))] = *(const uint4*)(
                Kh + ((size_t)((b * Hh + h) * Ss + sbase + srow)) * DHd + g8 * 8);
        }
        __syncthreads();

        f32x4 acc[4][4];
#pragma unroll
        for (int a = 0; a < 4; ++a)
#pragma unroll
          for (int s = 0; s < 4; ++s) acc[a][s] = (f32x4){0.f, 0.f, 0.f, 0.f};

#pragma unroll
        for (int kt = 0; kt < 2; ++kt)
#pragma unroll
          for (int st = 0; st < 4; ++st) {
            int srow = st * 16 + c;
            s16x8 kh = __builtin_bit_cast(s16x8,
                ((const uint4*)Klds)[srow * 8 + ((kt * 4 + g) ^ (srow & 7))]);
#pragma unroll
            for (int mt = 0; mt < 4; ++mt)
                acc[mt][st] = __builtin_amdgcn_mfma_f32_16x16x32_bf16(
                    qh[mt][kt], kh, acc[mt][st], 0, 0, 0);
          }

#pragma unroll
        for (int mt = 0; mt < 4; ++mt)
#pragma unroll
          for (int r = 0; r < 4; ++r) {
            float es = __builtin_exp2f(acc[mt][0][r]) + __builtin_exp2f(acc[mt][1][r])
                     + __builtin_exp2f(acc[mt][2][r]) + __builtin_exp2f(acc[mt][3][r]);
            es += __shfl_xor(es, 1); es += __shfl_xor(es, 2);
            es += __shfl_xor(es, 4); es += __shfl_xor(es, 8);
            d[mt][r] += es;
          }
        __syncthreads();
    }

    if (c == 0) {
#pragma unroll
        for (int mt = 0; mt < 4; ++mt)
#pragma unroll
          for (int r = 0; r < 4; ++r) {
            int row = mt * 16 + g * 4 + r;
            md[(((size_t)(b * Hh + h) * 2 + sh) * Pp + p) * Ll + row] = d[mt][r];
          }
    }
}

// ---------- pass B: exact scores (3-mfma) -> probs, heat, PV -----------------
__global__ __launch_bounds__(512) void passB_kernel(
        const float* __restrict__ q, const unsigned short* __restrict__ Kh,
        const unsigned short* __restrict__ Kl, const unsigned short* __restrict__ Vt,
        const float* __restrict__ md, float* __restrict__ heatp,
        float* __restrict__ outp, int i) {
    __shared__ unsigned short Khl_[64 * 64];   // 8KB
    __shared__ unsigned short Kll_[64 * 64];   // 8KB
    __shared__ unsigned short Vtl_[64 * 64];   // 8KB
    __shared__ unsigned short plds[8][64 * 32];// 32KB
    int bx = blockIdx.x;
    int b = bx >> 4, h = (bx >> 1) & 7, sh = bx & 1;
    int t = threadIdx.x, p = t >> 6, lane = t & 63, c = lane & 15, g = lane >> 4;
    const float* qb = q + (size_t)i * 262144;

    float rdf[4][4];
#pragma unroll
    for (int mt = 0; mt < 4; ++mt)
#pragma unroll
      for (int r = 0; r < 4; ++r) {
        int row = mt * 16 + g * 4 + r;
        size_t i0 = (((size_t)(b * Hh + h) * 2 + 0) * Pp + p) * Ll + row;
        size_t i1 = (((size_t)(b * Hh + h) * 2 + 1) * Pp + p) * Ll + row;
        rdf[mt][r] = 1.0f / (md[i0] + md[i1]);
      }

    s16x8 qh[4][2], ql[4][2];
#pragma unroll
    for (int mt = 0; mt < 4; ++mt)
#pragma unroll
      for (int kt = 0; kt < 2; ++kt) {
        const float* qp = qb + (size_t)(p * 64 + mt * 16 + c) * INN + h * 64 + kt * 32 + g * 8;
        s16x8 fh, fl;
#pragma unroll
        for (int e = 0; e < 8; ++e) {
            float v = qp[e] * KSC;
            unsigned short hi = f2bf(v);
            fh[e] = (short)hi;
            fl[e] = (short)f2bf(v - bf2f(hi));
        }
        qh[mt][kt] = fh; ql[mt][kt] = fl;
      }

    f32x4 o[4][4];
#pragma unroll
    for (int a = 0; a < 4; ++a)
#pragma unroll
      for (int s = 0; s < 4; ++s) o[a][s] = (f32x4){0.f, 0.f, 0.f, 0.f};

    for (int ch = 0; ch < 8; ++ch) {
        int sbase = sh * 512 + ch * 64;
        {
            int srow = t >> 3, g8 = t & 7;
            size_t src = ((size_t)((b * Hh + h) * Ss + sbase + srow)) * DHd + g8 * 8;
            int dst = srow * 8 + (g8 ^ (srow & 7));
            ((uint4*)Khl_)[dst] = *(const uint4*)(Kh + src);
            ((uint4*)Kll_)[dst] = *(const uint4*)(Kl + src);
            ((uint4*)Vtl_)[srow * 8 + (g8 ^ (srow & 7))] = *(const uint4*)(
                Vt + ((size_t)(b * Hh + h) * DHd + srow) * Ss + sbase + g8 * 8);
        }
        __syncthreads();

#pragma unroll
        for (int half = 0; half < 2; ++half) {
            f32x4 sacc[4][2];
#pragma unroll
            for (int a = 0; a < 4; ++a)
#pragma unroll
              for (int s = 0; s < 2; ++s) sacc[a][s] = (f32x4){0.f, 0.f, 0.f, 0.f};

#pragma unroll
            for (int kt = 0; kt < 2; ++kt)
#pragma unroll
              for (int s2 = 0; s2 < 2; ++s2) {
                int st = half * 2 + s2;
                int srow = st * 16 + c;
                int gi = srow * 8 + ((kt * 4 + g) ^ (srow & 7));
                s16x8 kh = __builtin_bit_cast(s16x8, ((const uint4*)Khl_)[gi]);
                s16x8 kl = __builtin_bit_cast(s16x8, ((const uint4*)Kll_)[gi]);
#pragma unroll
                for (int mt = 0; mt < 4; ++mt) {
                    sacc[mt][s2] = __builtin_amdgcn_mfma_f32_16x16x32_bf16(
                        qh[mt][kt], kh, sacc[mt][s2], 0, 0, 0);
                    sacc[mt][s2] = __builtin_amdgcn_mfma_f32_16x16x32_bf16(
                        qh[mt][kt], kl, sacc[mt][s2], 0, 0, 0);
                    sacc[mt][s2] = __builtin_amdgcn_mfma_f32_16x16x32_bf16(
                        ql[mt][kt], kh, sacc[mt][s2], 0, 0, 0);
                }
              }

#pragma unroll
            for (int s2 = 0; s2 < 2; ++s2) {
                int st = half * 2 + s2;
                float hs = 0.f;
#pragma unroll
                for (int mt = 0; mt < 4; ++mt)
#pragma unroll
                  for (int r = 0; r < 4; ++r) {
                    float pv = __builtin_exp2f(sacc[mt][s2][r]) * rdf[mt][r];
                    hs += pv;
                    int row = mt * 16 + g * 4 + r;
                    int colh = s2 * 16 + c;
                    plds[p][row * 32 + (((colh >> 3) ^ ((row >> 2) & 3)) << 3) + (colh & 7)]
                        = f2bf(pv);
                  }
                hs += __shfl_xor(hs, 16);
                hs += __shfl_xor(hs, 32);
                if (g == 0)
                    heatp[((size_t)(h * Bq + b) * Pp + p) * Ss + sbase + st * 16 + c] = hs;
            }

            s16x8 pa[4], vb[4];
#pragma unroll
            for (int mt = 0; mt < 4; ++mt) {
                int row = mt * 16 + c;
                uint4 wv = ((const uint4*)plds[p])[row * 4 + (g ^ ((row >> 2) & 3))];
                pa[mt] = __builtin_bit_cast(s16x8, wv);
            }
#pragma unroll
            for (int dht = 0; dht < 4; ++dht) {
                int row = dht * 16 + c;
                uint4 wv = ((const uint4*)Vtl_)[row * 8 + ((half * 4 + g) ^ (c & 7))];
                vb[dht] = __builtin_bit_cast(s16x8, wv);
            }
#pragma unroll
            for (int mt = 0; mt < 4; ++mt)
#pragma unroll
              for (int dht = 0; dht < 4; ++dht)
                o[mt][dht] = __builtin_amdgcn_mfma_f32_16x16x32_bf16(
                    pa[mt], vb[dht], o[mt][dht], 0, 0, 0);
        }
        __syncthreads();
    }

#pragma unroll
    for (int mt = 0; mt < 4; ++mt)
#pragma unroll
      for (int dht = 0; dht < 4; ++dht)
#pragma unroll
        for (int r = 0; r < 4; ++r) {
            int row = mt * 16 + g * 4 + r;
            outp[(((((size_t)sh * Bq + b) * Hh + h) * Pp + p) * Ll + row) * DHd
                 + dht * 16 + c] = o[mt][dht][r];
        }
}

// ---------- finalize: deterministic argmax + dist ----------------------------
__global__ __launch_bounds__(256) void fin_kernel(
        const float* __restrict__ heatp, const float* __restrict__ outp,
        const float* __restrict__ q, float* __restrict__ out, int i) {
    __shared__ float rv[4];
    __shared__ int   ri[4];
    __shared__ float rs[4];
    int b = blockIdx.x >> 3, p = blockIdx.x & 7;
    int t = threadIdx.x, w = t >> 6, lane = t & 63;
    const float* qb = q + (size_t)i * 262144;

    float best = -1e30f; int bidx = 0;
    for (int s = t; s < Ss; s += 256) {
        float hv = 0.f;
#pragma unroll
        for (int h = 0; h < 8; ++h)
            hv += heatp[((size_t)(h * Bq + b) * Pp + p) * Ss + s];
        if (hv > best) { best = hv; bidx = s; }
    }
#pragma unroll
    for (int off = 1; off < 64; off <<= 1) {
        float vo = __shfl_xor(best, off);
        int   io = __shfl_xor(bidx, off);
        if (vo > best || (vo == best && io < bidx)) { best = vo; bidx = io; }
    }
    if (lane == 0) { rv[w] = best; ri[w] = bidx; }
    __syncthreads();
    if (t == 0) {
#pragma unroll
        for (int u = 1; u < 4; ++u)
            if (rv[u] > best || (rv[u] == best && ri[u] < bidx)) { best = rv[u]; bidx = ri[u]; }
        out[384 + b * 24 + i * Pp + p] = (float)bidx;
    }

    const size_t HALF = (size_t)Bq * Hh * Pp * Ll * DHd;
    float sum = 0.f;
    for (int idx = t; idx < Ll * INN; idx += 256) {
        int l = idx >> 9, n = idx & 511;
        int hh = n >> 6, dh = n & 63;
        float qv = qb[(size_t)(p * Ll + l) * INN + n];
        size_t base = ((((size_t)b * Hh + hh) * Pp + p) * Ll + l) * DHd + dh;
        float ov = outp[base] + outp[HALF + base];
        float df = qv - ov;
        sum += df * df;
    }
#pragma unroll
    for (int off = 32; off; off >>= 1) sum += __shfl_down(sum, off);
    if (lane == 0) rs[w] = sum;
    __syncthreads();
    if (t == 0)
        out[b * 24 + i * Pp + p] = (rs[0] + rs[1] + rs[2] + rs[3]) / (float)(Ll * INN);
}

extern "C" void kernel_launch(void* const* d_in, const int* in_sizes, int n_in,
                              void* d_out, int out_size, void* d_ws, size_t ws_size,
                              hipStream_t stream) {
    const float* x    = (const float*)d_in[0];
    const float* prot = (const float*)d_in[1];
    const float* Wq   = (const float*)d_in[2];
    const float* Wk   = (const float*)d_in[3];
    const float* Wv   = (const float*)d_in[4];
    float* out = (float*)d_out;
    float* ws  = (float*)d_ws;

    float* qbuf  = ws;                      // 3*262144
    float* md    = qbuf + 786432;           // 131072
    float* heatp = md + 131072;             // 1048576
    float* outp  = heatp + 1048576;         // 8388608
    unsigned short* Kh  = (unsigned short*)(outp + 8388608);  // 8388608 u16
    unsigned short* Kl  = Kh + 8388608;
    unsigned short* Vt  = Kl + 8388608;
    unsigned short* Wth = Vt + 8388608;     // 3*131072
    unsigned short* Wtl = Wth + 393216;
    unsigned short* Wvh = Wtl + 393216;

    wsplit_kernel<<<48,   256, 0, stream>>>(Wk, Wv, Wth, Wtl, Wvh);
    qk_kernel    <<<1536, 256, 0, stream>>>(prot, Wq, qbuf);
    for (int i = 0; i < 3; ++i) {
        kv_kernel   <<<256, 512, 0, stream>>>(x, Wth, Wtl, Wvh, Kh, Kl, Vt, i);
        passA_kernel<<<256, 512, 0, stream>>>(qbuf, Kh, md, i);
        passB_kernel<<<256, 512, 0, stream>>>(qbuf, Kh, Kl, Vt, md, heatp, outp, i);
        fin_kernel  <<<128, 256, 0, stream>>>(heatp, outp, qbuf, out, i);
    }
}

// Round 4
// 641.131 us; speedup vs baseline: 19.4507x; 1.2663x over previous
//
#include <hip/hip_runtime.h>
#include <hip/hip_bf16.h>

#define Bq 16
#define Cc 256
#define Ss 1024
#define Ll 64
#define Hh 8
#define DHd 64
#define INN 512
#define Pp 8
// SCALE * log2(e) folded into q so scores are in log2 domain
#define KSC 0.18033688011111772f

typedef short s16x8 __attribute__((ext_vector_type(8)));
typedef float f32x4 __attribute__((ext_vector_type(4)));

__device__ __forceinline__ unsigned short f2bf(float f) {
    unsigned u = __builtin_bit_cast(unsigned, f);
    u += 0x7FFF + ((u >> 16) & 1);
    return (unsigned short)(u >> 16);
}
__device__ __forceinline__ float bf2f(unsigned short h) {
    return __builtin_bit_cast(float, (unsigned)h << 16);
}

// ---------- W transpose + bf16 hi/lo split: Wk -> Wth/Wtl, Wv -> Wvh ---------
__global__ __launch_bounds__(256) void wsplit_kernel(
        const float* __restrict__ Wk, const float* __restrict__ Wv,
        unsigned short* __restrict__ Wth, unsigned short* __restrict__ Wtl,
        unsigned short* __restrict__ Wvh) {
    __shared__ float tile[64][65];
    int blk = blockIdx.x;              // 48 = i*16 + mat*8 + ns
    int i = blk >> 4, rem = blk & 15, mat = rem >> 3, ns = rem & 7;
    int n0 = ns * 64, t = threadIdx.x;
    const float* W = (mat == 0 ? Wk : Wv) + (size_t)i * Cc * INN;
    for (int cb = 0; cb < 4; ++cb) {
        int c0 = cb * 64;
#pragma unroll
        for (int it = 0; it < 16; ++it) {
            int idx = t + it * 256; int cc = idx >> 6, nn = idx & 63;
            tile[cc][nn] = W[(size_t)(c0 + cc) * INN + n0 + nn];
        }
        __syncthreads();
#pragma unroll
        for (int it = 0; it < 16; ++it) {
            int idx = t + it * 256; int nn = idx >> 6, cc = idx & 63;
            float v = tile[cc][nn];
            unsigned short hi = f2bf(v);
            size_t o = (size_t)i * 131072 + (size_t)(n0 + nn) * Cc + c0 + cc;
            if (mat == 0) { Wth[o] = hi; Wtl[o] = f2bf(v - bf2f(hi)); }
            else          { Wvh[o] = hi; }
        }
        __syncthreads();
    }
}

// ---------- q = pp @ Wq[i] : f32, 4 l-rows per block for W reuse -------------
__global__ __launch_bounds__(256) void qk_kernel(const float* __restrict__ prot,
                                                 const float* __restrict__ Wq,
                                                 float* __restrict__ qout) {
    __shared__ float pcol[4][256];
    int blk = blockIdx.x;              // 384 = i*128 + p*16 + l4
    int i = blk >> 7, rem = blk & 127, p = rem >> 4, l4 = rem & 15;
    int t = threadIdx.x;
    const float* W = Wq + (size_t)i * Cc * INN;
#pragma unroll
    for (int it = 0; it < 4; ++it) {
        int idx = t + it * 256; int ll = idx >> 8, cc = idx & 255;
        pcol[ll][cc] = prot[((size_t)(i * Pp + p) * Cc + cc) * Ll + l4 * 4 + ll];
    }
    __syncthreads();
    float a0[4] = {0, 0, 0, 0}, a1[4] = {0, 0, 0, 0};
#pragma unroll 4
    for (int c = 0; c < Cc; ++c) {
        float w0 = W[c * INN + t], w1 = W[c * INN + t + 256];
#pragma unroll
        for (int ll = 0; ll < 4; ++ll) {
            a0[ll] += pcol[ll][c] * w0;
            a1[ll] += pcol[ll][c] * w1;
        }
    }
#pragma unroll
    for (int ll = 0; ll < 4; ++ll) {
        float* qo = qout + (size_t)i * 262144 + (size_t)(p * 64 + l4 * 4 + ll) * INN;
        qo[t] = a0[ll]; qo[t + 256] = a1[ll];
    }
}

// ---------- K,V projection: x LDS-staged, wave-per-h, coalesced stores -------
__device__ __forceinline__ int xs_idx4(int s, int col4) {   // uint4 index
    return s * 64 + (col4 ^ (s & 7));
}

__global__ __launch_bounds__(512, 2) void kv_kernel(
        const float* __restrict__ x, const unsigned short* __restrict__ WthA,
        const unsigned short* __restrict__ WtlA, const unsigned short* __restrict__ WvhA,
        unsigned short* __restrict__ Kh, unsigned short* __restrict__ Kl,
        unsigned short* __restrict__ Vt, int i) {
    __shared__ unsigned xs[64 * 256];      // 64KB: [s][ch] packed bf16 hi|lo
    int blk = blockIdx.x;                  // 256 = b*16 + sb
    int b = blk >> 4, sb = blk & 15;
    int t = threadIdx.x, w = t >> 6, lane = t & 63, c = lane & 15, g = lane >> 4;
    int h = w;                             // wave <-> head
    const unsigned short* wth = WthA + (size_t)i * 131072;
    const unsigned short* wtl = WtlA + (size_t)i * 131072;
    const unsigned short* wvh = WvhA + (size_t)i * 131072;

    // ---- stage x tile (256 ch x 64 s) as packed hi|lo, swizzled ----
#pragma unroll
    for (int it = 0; it < 8; ++it) {
        int unit = t + it * 512;           // 4096 float4 units
        int ch = unit >> 4, sq = unit & 15;
        float4 v = *(const float4*)(x + ((size_t)b * Cc + ch) * Ss + sb * 64 + sq * 4);
        float vv[4] = {v.x, v.y, v.z, v.w};
#pragma unroll
        for (int e = 0; e < 4; ++e) {
            int s = sq * 4 + e;
            unsigned short hi = f2bf(vv[e]);
            unsigned short lo = f2bf(vv[e] - bf2f(hi));
            xs[s * 256 + ((ch >> 2) ^ (s & 7)) * 4 + (ch & 3)] =
                ((unsigned)hi << 16) | lo;
        }
    }
    __syncthreads();

    f32x4 accK[4][4], accV[4][4];          // accK[nt(dh)][st(s)], accV[st][nt]
#pragma unroll
    for (int a = 0; a < 4; ++a)
#pragma unroll
      for (int s = 0; s < 4; ++s) {
        accK[a][s] = (f32x4){0.f, 0.f, 0.f, 0.f};
        accV[a][s] = (f32x4){0.f, 0.f, 0.f, 0.f};
      }

#pragma unroll
    for (int cs = 0; cs < 8; ++cs) {
        // x fragments for 4 s-tiles: lane c -> s = st*16+c, elems = ch cs*32+g*8+e
        s16x8 xh[4], xl[4];
#pragma unroll
        for (int st = 0; st < 4; ++st) {
            int s = st * 16 + c;
            uint4 q0 = ((const uint4*)xs)[xs_idx4(s, cs * 8 + g * 2)];
            uint4 q1 = ((const uint4*)xs)[xs_idx4(s, cs * 8 + g * 2 + 1)];
            unsigned wrd[8] = {q0.x, q0.y, q0.z, q0.w, q1.x, q1.y, q1.z, q1.w};
            s16x8 fh, fl;
#pragma unroll
            for (int e = 0; e < 8; ++e) {
                fh[e] = (short)(wrd[e] >> 16);
                fl[e] = (short)(wrd[e] & 0xFFFF);
            }
            xh[st] = fh; xl[st] = fl;
        }
        int c0 = cs * 32 + g * 8;
#pragma unroll
        for (int nt = 0; nt < 4; ++nt) {
            int n = h * 64 + nt * 16 + c;
            s16x8 bh = __builtin_bit_cast(s16x8, *(const uint4*)(wth + (size_t)n * Cc + c0));
            s16x8 bl = __builtin_bit_cast(s16x8, *(const uint4*)(wtl + (size_t)n * Cc + c0));
            s16x8 bv = __builtin_bit_cast(s16x8, *(const uint4*)(wvh + (size_t)n * Cc + c0));
#pragma unroll
            for (int st = 0; st < 4; ++st) {
                accK[nt][st] = __builtin_amdgcn_mfma_f32_16x16x32_bf16(bh, xh[st], accK[nt][st], 0, 0, 0);
                accK[nt][st] = __builtin_amdgcn_mfma_f32_16x16x32_bf16(bh, xl[st], accK[nt][st], 0, 0, 0);
                accK[nt][st] = __builtin_amdgcn_mfma_f32_16x16x32_bf16(bl, xh[st], accK[nt][st], 0, 0, 0);
                accV[st][nt] = __builtin_amdgcn_mfma_f32_16x16x32_bf16(xh[st], bv, accV[st][nt], 0, 0, 0);
            }
        }
    }

    // ---- stores: K rows=dh (4 consecutive), V rows=s (4 consecutive) ----
#pragma unroll
    for (int nt = 0; nt < 4; ++nt)
#pragma unroll
      for (int st = 0; st < 4; ++st) {
        // K: s = sb*64 + st*16 + c ; dh = nt*16 + g*4 + r
        size_t kb = ((size_t)(b * Hh + h) * Ss + sb * 64 + st * 16 + c) * DHd
                    + nt * 16 + g * 4;
        unsigned short h0 = f2bf(accK[nt][st][0]), h1 = f2bf(accK[nt][st][1]);
        unsigned short h2 = f2bf(accK[nt][st][2]), h3 = f2bf(accK[nt][st][3]);
        uint2 ph; ph.x = h0 | ((unsigned)h1 << 16); ph.y = h2 | ((unsigned)h3 << 16);
        *(uint2*)(Kh + kb) = ph;
        unsigned short l0 = f2bf(accK[nt][st][0] - bf2f(h0));
        unsigned short l1 = f2bf(accK[nt][st][1] - bf2f(h1));
        unsigned short l2 = f2bf(accK[nt][st][2] - bf2f(h2));
        unsigned short l3 = f2bf(accK[nt][st][3] - bf2f(h3));
        uint2 pl; pl.x = l0 | ((unsigned)l1 << 16); pl.y = l2 | ((unsigned)l3 << 16);
        *(uint2*)(Kl + kb) = pl;
        // V^T: dh = nt*16 + c ; s = sb*64 + st*16 + g*4 + r
        size_t vb = ((size_t)(b * Hh + h) * DHd + nt * 16 + c) * Ss
                    + sb * 64 + st * 16 + g * 4;
        unsigned short v0 = f2bf(accV[st][nt][0]), v1 = f2bf(accV[st][nt][1]);
        unsigned short v2 = f2bf(accV[st][nt][2]), v3 = f2bf(accV[st][nt][3]);
        uint2 pv; pv.x = v0 | ((unsigned)v1 << 16); pv.y = v2 | ((unsigned)v3 << 16);
        *(uint2*)(Vt + vb) = pv;
      }
}

// ---------- pass A: hi-only scores -> d = sum exp2(s), no max ----------------
__global__ __launch_bounds__(512) void passA_kernel(
        const float* __restrict__ q, const unsigned short* __restrict__ Kh,
        float* __restrict__ md, int i) {
    __shared__ unsigned short Klds[64 * 64];   // 8KB swizzled
    int bx = blockIdx.x;
    int b = bx >> 4, h = (bx >> 1) & 7, sh = bx & 1;
    int t = threadIdx.x, p = t >> 6, lane = t & 63, c = lane & 15, g = lane >> 4;
    const float* qb = q + (size_t)i * 262144;

    s16x8 qh[4][2];
#pragma unroll
    for (int mt = 0; mt < 4; ++mt)
#pragma unroll
      for (int kt = 0; kt < 2; ++kt) {
        const float* qp = qb + (size_t)(p * 64 + mt * 16 + c) * INN + h * 64 + kt * 32 + g * 8;
        s16x8 f;
#pragma unroll
        for (int e = 0; e < 8; ++e) f[e] = (short)f2bf(qp[e] * KSC);
        qh[mt][kt] = f;
      }

    float d[4][4];
#pragma unroll
    for (int a = 0; a < 4; ++a)
#pragma unroll
      for (int r = 0; r < 4; ++r) d[a][r] = 0.f;

    for (int ch = 0; ch < 8; ++ch) {
        int sbase = sh * 512 + ch * 64;
        {
            int srow = t >> 3, g8 = t & 7;
            ((uint4*)Klds)[srow * 8 + (g8 ^ (srow & 7))] = *(const uint4*)(
                Kh + ((size_t)((b * Hh + h) * Ss + sbase + srow)) * DHd + g8 * 8);
        }
        __syncthreads();

        f32x4 acc[4][4];
#pragma unroll
        for (int a = 0; a < 4; ++a)
#pragma unroll
          for (int s = 0; s < 4; ++s) acc[a][s] = (f32x4){0.f, 0.f, 0.f, 0.f};

#pragma unroll
        for (int kt = 0; kt < 2; ++kt)
#pragma unroll
          for (int st = 0; st < 4; ++st) {
            int srow = st * 16 + c;
            s16x8 kh = __builtin_bit_cast(s16x8,
                ((const uint4*)Klds)[srow * 8 + ((kt * 4 + g) ^ (srow & 7))]);
#pragma unroll
            for (int mt = 0; mt < 4; ++mt)
                acc[mt][st] = __builtin_amdgcn_mfma_f32_16x16x32_bf16(
                    qh[mt][kt], kh, acc[mt][st], 0, 0, 0);
          }

#pragma unroll
        for (int mt = 0; mt < 4; ++mt)
#pragma unroll
          for (int r = 0; r < 4; ++r) {
            float es = __builtin_exp2f(acc[mt][0][r]) + __builtin_exp2f(acc[mt][1][r])
                     + __builtin_exp2f(acc[mt][2][r]) + __builtin_exp2f(acc[mt][3][r]);
            es += __shfl_xor(es, 1); es += __shfl_xor(es, 2);
            es += __shfl_xor(es, 4); es += __shfl_xor(es, 8);
            d[mt][r] += es;
          }
        __syncthreads();
    }

    if (c == 0) {
#pragma unroll
        for (int mt = 0; mt < 4; ++mt)
#pragma unroll
          for (int r = 0; r < 4; ++r) {
            int row = mt * 16 + g * 4 + r;
            md[(((size_t)(b * Hh + h) * 2 + sh) * Pp + p) * Ll + row] = d[mt][r];
          }
    }
}

// ---------- pass B: exact scores (3-mfma) -> probs, heat, PV -----------------
__global__ __launch_bounds__(512) void passB_kernel(
        const float* __restrict__ q, const unsigned short* __restrict__ Kh,
        const unsigned short* __restrict__ Kl, const unsigned short* __restrict__ Vt,
        const float* __restrict__ md, float* __restrict__ heatp,
        unsigned short* __restrict__ outp, int i) {
    __shared__ unsigned short Khl_[64 * 64];   // 8KB
    __shared__ unsigned short Kll_[64 * 64];   // 8KB
    __shared__ unsigned short Vtl_[64 * 64];   // 8KB
    __shared__ unsigned short plds[8][64 * 32];// 32KB
    int bx = blockIdx.x;
    int b = bx >> 4, h = (bx >> 1) & 7, sh = bx & 1;
    int t = threadIdx.x, p = t >> 6, lane = t & 63, c = lane & 15, g = lane >> 4;
    const float* qb = q + (size_t)i * 262144;

    float rdf[4][4];
#pragma unroll
    for (int mt = 0; mt < 4; ++mt)
#pragma unroll
      for (int r = 0; r < 4; ++r) {
        int row = mt * 16 + g * 4 + r;
        size_t i0 = (((size_t)(b * Hh + h) * 2 + 0) * Pp + p) * Ll + row;
        size_t i1 = (((size_t)(b * Hh + h) * 2 + 1) * Pp + p) * Ll + row;
        rdf[mt][r] = 1.0f / (md[i0] + md[i1]);
      }

    s16x8 qh[4][2], ql[4][2];
#pragma unroll
    for (int mt = 0; mt < 4; ++mt)
#pragma unroll
      for (int kt = 0; kt < 2; ++kt) {
        const float* qp = qb + (size_t)(p * 64 + mt * 16 + c) * INN + h * 64 + kt * 32 + g * 8;
        s16x8 fh, fl;
#pragma unroll
        for (int e = 0; e < 8; ++e) {
            float v = qp[e] * KSC;
            unsigned short hi = f2bf(v);
            fh[e] = (short)hi;
            fl[e] = (short)f2bf(v - bf2f(hi));
        }
        qh[mt][kt] = fh; ql[mt][kt] = fl;
      }

    f32x4 o[4][4];
#pragma unroll
    for (int a = 0; a < 4; ++a)
#pragma unroll
      for (int s = 0; s < 4; ++s) o[a][s] = (f32x4){0.f, 0.f, 0.f, 0.f};

    for (int ch = 0; ch < 8; ++ch) {
        int sbase = sh * 512 + ch * 64;
        {
            int srow = t >> 3, g8 = t & 7;
            size_t src = ((size_t)((b * Hh + h) * Ss + sbase + srow)) * DHd + g8 * 8;
            int dst = srow * 8 + (g8 ^ (srow & 7));
            ((uint4*)Khl_)[dst] = *(const uint4*)(Kh + src);
            ((uint4*)Kll_)[dst] = *(const uint4*)(Kl + src);
            ((uint4*)Vtl_)[srow * 8 + (g8 ^ (srow & 7))] = *(const uint4*)(
                Vt + ((size_t)(b * Hh + h) * DHd + srow) * Ss + sbase + g8 * 8);
        }
        __syncthreads();

#pragma unroll
        for (int half = 0; half < 2; ++half) {
            f32x4 sacc[4][2];
#pragma unroll
            for (int a = 0; a < 4; ++a)
#pragma unroll
              for (int s = 0; s < 2; ++s) sacc[a][s] = (f32x4){0.f, 0.f, 0.f, 0.f};

#pragma unroll
            for (int kt = 0; kt < 2; ++kt)
#pragma unroll
              for (int s2 = 0; s2 < 2; ++s2) {
                int st = half * 2 + s2;
                int srow = st * 16 + c;
                int gi = srow * 8 + ((kt * 4 + g) ^ (srow & 7));
                s16x8 kh = __builtin_bit_cast(s16x8, ((const uint4*)Khl_)[gi]);
                s16x8 kl = __builtin_bit_cast(s16x8, ((const uint4*)Kll_)[gi]);
#pragma unroll
                for (int mt = 0; mt < 4; ++mt) {
                    sacc[mt][s2] = __builtin_amdgcn_mfma_f32_16x16x32_bf16(
                        qh[mt][kt], kh, sacc[mt][s2], 0, 0, 0);
                    sacc[mt][s2] = __builtin_amdgcn_mfma_f32_16x16x32_bf16(
                        qh[mt][kt], kl, sacc[mt][s2], 0, 0, 0);
                    sacc[mt][s2] = __builtin_amdgcn_mfma_f32_16x16x32_bf16(
                        ql[mt][kt], kh, sacc[mt][s2], 0, 0, 0);
                }
              }

#pragma unroll
            for (int s2 = 0; s2 < 2; ++s2) {
                int st = half * 2 + s2;
                float hs = 0.f;
#pragma unroll
                for (int mt = 0; mt < 4; ++mt)
#pragma unroll
                  for (int r = 0; r < 4; ++r) {
                    float pv = __builtin_exp2f(sacc[mt][s2][r]) * rdf[mt][r];
                    hs += pv;
                    int row = mt * 16 + g * 4 + r;
                    int colh = s2 * 16 + c;
                    plds[p][row * 32 + (((colh >> 3) ^ ((row >> 2) & 3)) << 3) + (colh & 7)]
                        = f2bf(pv);
                  }
                hs += __shfl_xor(hs, 16);
                hs += __shfl_xor(hs, 32);
                if (g == 0)
                    heatp[((size_t)(h * Bq + b) * Pp + p) * Ss + sbase + st * 16 + c] = hs;
            }

            s16x8 pa[4], vb[4];
#pragma unroll
            for (int mt = 0; mt < 4; ++mt) {
                int row = mt * 16 + c;
                uint4 wv = ((const uint4*)plds[p])[row * 4 + (g ^ ((row >> 2) & 3))];
                pa[mt] = __builtin_bit_cast(s16x8, wv);
            }
#pragma unroll
            for (int dht = 0; dht < 4; ++dht) {
                int row = dht * 16 + c;
                uint4 wv = ((const uint4*)Vtl_)[row * 8 + ((half * 4 + g) ^ (c & 7))];
                vb[dht] = __builtin_bit_cast(s16x8, wv);
            }
#pragma unroll
            for (int mt = 0; mt < 4; ++mt)
#pragma unroll
              for (int dht = 0; dht < 4; ++dht)
                o[mt][dht] = __builtin_amdgcn_mfma_f32_16x16x32_bf16(
                    pa[mt], vb[dht], o[mt][dht], 0, 0, 0);
        }
        __syncthreads();
    }

#pragma unroll
    for (int mt = 0; mt < 4; ++mt)
#pragma unroll
      for (int dht = 0; dht < 4; ++dht)
#pragma unroll
        for (int r = 0; r < 4; ++r) {
            int row = mt * 16 + g * 4 + r;
            outp[(((((size_t)sh * Bq + b) * Hh + h) * Pp + p) * Ll + row) * DHd
                 + dht * 16 + c] = f2bf(o[mt][dht][r]);
        }
}

// ---------- finalize: deterministic argmax + dist ----------------------------
__global__ __launch_bounds__(256) void fin_kernel(
        const float* __restrict__ heatp, const unsigned short* __restrict__ outp,
        const float* __restrict__ q, float* __restrict__ out, int i) {
    __shared__ float rv[4];
    __shared__ int   ri[4];
    __shared__ float rs[4];
    int b = blockIdx.x >> 3, p = blockIdx.x & 7;
    int t = threadIdx.x, w = t >> 6, lane = t & 63;
    const float* qb = q + (size_t)i * 262144;

    float best = -1e30f; int bidx = 0;
    for (int s = t; s < Ss; s += 256) {
        float hv = 0.f;
#pragma unroll
        for (int h = 0; h < 8; ++h)
            hv += heatp[((size_t)(h * Bq + b) * Pp + p) * Ss + s];
        if (hv > best) { best = hv; bidx = s; }
    }
#pragma unroll
    for (int off = 1; off < 64; off <<= 1) {
        float vo = __shfl_xor(best, off);
        int   io = __shfl_xor(bidx, off);
        if (vo > best || (vo == best && io < bidx)) { best = vo; bidx = io; }
    }
    if (lane == 0) { rv[w] = best; ri[w] = bidx; }
    __syncthreads();
    if (t == 0) {
#pragma unroll
        for (int u = 1; u < 4; ++u)
            if (rv[u] > best || (rv[u] == best && ri[u] < bidx)) { best = rv[u]; bidx = ri[u]; }
        out[384 + b * 24 + i * Pp + p] = (float)bidx;
    }

    const size_t HALF = (size_t)Bq * Hh * Pp * Ll * DHd;
    float sum = 0.f;
    for (int idx = t; idx < Ll * INN; idx += 256) {
        int l = idx >> 9, n = idx & 511;
        int hh = n >> 6, dh = n & 63;
        float qv = qb[(size_t)(p * Ll + l) * INN + n];
        size_t base = ((((size_t)b * Hh + hh) * Pp + p) * Ll + l) * DHd + dh;
        float ov = bf2f(outp[base]) + bf2f(outp[HALF + base]);
        float df = qv - ov;
        sum += df * df;
    }
#pragma unroll
    for (int off = 32; off; off >>= 1) sum += __shfl_down(sum, off);
    if (lane == 0) rs[w] = sum;
    __syncthreads();
    if (t == 0)
        out[b * 24 + i * Pp + p] = (rs[0] + rs[1] + rs[2] + rs[3]) / (float)(Ll * INN);
}

extern "C" void kernel_launch(void* const* d_in, const int* in_sizes, int n_in,
                              void* d_out, int out_size, void* d_ws, size_t ws_size,
                              hipStream_t stream) {
    const float* x    = (const float*)d_in[0];
    const float* prot = (const float*)d_in[1];
    const float* Wq   = (const float*)d_in[2];
    const float* Wk   = (const float*)d_in[3];
    const float* Wv   = (const float*)d_in[4];
    float* out = (float*)d_out;
    float* ws  = (float*)d_ws;

    float* qbuf  = ws;                      // 3*262144 f32
    float* md    = qbuf + 786432;           // 131072 f32
    float* heatp = md + 131072;             // 1048576 f32
    unsigned short* outp = (unsigned short*)(heatp + 1048576);   // 8388608 u16
    unsigned short* Kh  = outp + 8388608;   // 8388608 u16
    unsigned short* Kl  = Kh + 8388608;
    unsigned short* Vt  = Kl + 8388608;
    unsigned short* Wth = Vt + 8388608;     // 3*131072 u16
    unsigned short* Wtl = Wth + 393216;
    unsigned short* Wvh = Wtl + 393216;

    wsplit_kernel<<<48,  256, 0, stream>>>(Wk, Wv, Wth, Wtl, Wvh);
    qk_kernel    <<<384, 256, 0, stream>>>(prot, Wq, qbuf);
    for (int i = 0; i < 3; ++i) {
        kv_kernel   <<<256, 512, 0, stream>>>(x, Wth, Wtl, Wvh, Kh, Kl, Vt, i);
        passA_kernel<<<256, 512, 0, stream>>>(qbuf, Kh, md, i);
        passB_kernel<<<256, 512, 0, stream>>>(qbuf, Kh, Kl, Vt, md, heatp, outp, i);
        fin_kernel  <<<128, 256, 0, stream>>>(heatp, outp, qbuf, out, i);
    }
}